// Round 12
// baseline (205.461 us; speedup 1.0000x reference)
//
#include <hip/hip_runtime.h>
#include <hip/hip_fp16.h>

// Conv2d 3x3 s1 p1, NCHW fp32: N=32, Cin=256, H=W=56, Cout=256.
// R12 (= R11 resubmit after infra failure): fp16 path. A (weights) go
// global->VGPR batched PER CHUNK (18 loads, fragment-major wpf, L2-hot,
// 9-tap window hides latency) -> A out of LDS entirely.
// MFMA 32x32x16_f16 (m2 x j2, wave 64co x 64sp). B (x) from dbuf LDS.
// DS reads halve vs R10 (1152/block); 1 barrier per chunk (8 total).

#define NB   32
#define CIN  256
#define HH   56
#define WW   56
#define COUT 256

typedef unsigned short u16;
typedef __attribute__((ext_vector_type(8)))  _Float16 f16x8;
typedef __attribute__((ext_vector_type(16))) float    f32x16;

#define XS_ELEMS  (32u*58u*58u*256u)          // padded NHWC fp16
#define XS_BYTES  ((size_t)XS_ELEMS*2u)
#define WPF_ELEMS (8u*8u*2u*9u*64u*8u)        // [ck8][cg8][ks2][tap9][lane64][8]
#define WPF_BYTES ((size_t)WPF_ELEMS*2u)      // 1.18 MB
#define WS_NEED   (XS_BYTES + WPF_BYTES)

__device__ __forceinline__ void gld16(const u16* g, u16* l) {
    __builtin_amdgcn_global_load_lds(
        (const __attribute__((address_space(1))) void*)g,
        (__attribute__((address_space(3))) void*)l, 16, 0, 0);
}

__device__ __forceinline__ u16 f16_bits(float v) {
    _Float16 h = (_Float16)v;                // RNE
    return *reinterpret_cast<u16*>(&h);
}

// ---- pre-pass 0: zero halo border cells of xs ----
__global__ __launch_bounds__(256) void halo_zero(u16* __restrict__ xh) {
    unsigned i = blockIdx.x*256u + threadIdx.x;   // img*228*32 + cell*32 + g
    if (i >= 32u*228u*32u) return;
    unsigned g    = i & 31u;
    unsigned cell = (i >> 5) % 228u;
    unsigned img  = i / (228u*32u);
    unsigned h, w;
    if      (cell < 58)  { h = 0;                w = cell; }
    else if (cell < 116) { h = 57;               w = cell - 58; }
    else if (cell < 172) { h = 1 + (cell - 116); w = 0; }
    else                 { h = 1 + (cell - 172); w = 57; }
    unsigned o = ((img*58u + h)*58u + w)*256u + g*8u;
    uint4 z = {0u,0u,0u,0u};
    *reinterpret_cast<uint4*>(&xh[o]) = z;
}

// ---- pre-pass 1: x (NCHW f32) -> xs (padded NHWC fp16) ----
__global__ __launch_bounds__(256) void xcvt(const float* __restrict__ x,
                                            u16* __restrict__ xh) {
    __shared__ float tile[32][57];
    const int t  = threadIdx.x;
    const int b  = blockIdx.x;              // n*(8*56) + cg*56 + h
    const int n  = b / (8*56);
    const int cg = (b / 56) % 8;
    const int h  = b % 56;
    const float* src = x + ((size_t)n*CIN + cg*32) * 3136 + (unsigned)h*56;
    #pragma unroll
    for (int k = 0; k < 7; ++k) {           // 32*56 = 1792 = 7*256
        int idx = t + k*256;
        int c = idx / 56, w = idx % 56;
        tile[c][w] = src[(unsigned)c*3136 + w];
    }
    __syncthreads();
    const unsigned obase = (((unsigned)n*58 + h + 1)*58 + 1)*256 + cg*32;
    #pragma unroll
    for (int k = 0; k < 7; ++k) {
        int idx = t + k*256;
        int w = idx / 32, c = idx % 32;
        xh[obase + (unsigned)w*256 + c] = f16_bits(tile[c][w]);
    }
}

// ---- pre-pass 2: w (OIHW f32) -> wpf fragment-major fp16 ----
// idx = ((((ck*8 + cg)*2 + ks)*9 + tap)*64 + lane)*8 + jj
// co = cg*32 + (lane&31); ci = ck*32 + ks*16 + (lane>>5)*8 + jj
__global__ __launch_bounds__(256) void wcvt(const float* __restrict__ w,
                                            u16* __restrict__ wpf) {
    unsigned i = blockIdx.x*256u + threadIdx.x;
    if (i >= WPF_ELEMS) return;
    unsigned jj   = i & 7u;
    unsigned lane = (i >> 3) & 63u;
    unsigned u    = i >> 9;           // (((ck*8+cg)*2+ks)*9+tap)
    unsigned tap  = u % 9u;
    unsigned v    = u / 9u;
    unsigned ks   = v & 1u;
    unsigned cg   = (v >> 1) & 7u;
    unsigned ck   = v >> 4;
    unsigned co   = cg*32u + (lane & 31u);
    unsigned ci   = ck*32u + ks*16u + (lane >> 5)*8u + jj;
    wpf[i] = f16_bits(w[(size_t)co*2304u + ci*9u + tap]);
}

// ---- main conv kernel ----
// Block: 256 thr / 4 waves; tile 128co x 2img x (8x8 sp). Wave: 64co x 64sp.
// MFMA 32x32x16_f16 (maps HW-verified R5/R6): A row=lane&31 (co),
// k=(lane>>5)*8+j; B col=lane&31 (sp); C/D col=lane&31,
// row=(reg&3)+8*(reg>>2)+4*(lane>>5).
// A: global->VGPR, 18 loads per (chunk,ks), static-unrolled (no dyn idx).
// B: sXc[2][200cell][32ci] dbuf LDS; slot = cell*32 + (ks*2+khi)*8 u16.
__global__ __launch_bounds__(256, 2) void conv_mfma(
    const u16* __restrict__ xs,
    const u16* __restrict__ wpf,
    const float* __restrict__ bias, float* __restrict__ y) {
    __shared__ __align__(16) u16 sXc[2][6400];   // 2 x 12.8 KB

    const int t    = threadIdx.x;
    const int lane = t & 63, wid = t >> 6;
    const int wc   = wid >> 1;          // co half (0/1)
    const int iwv  = wid & 1;           // image   (0/1)
    const int s5   = lane & 31;
    const int khi  = lane >> 5;

    const int bid  = blockIdx.x;        // (sp*16 + nt)*2 + co_t (co_t fastest)
    const int co_t = bid & 1;
    const int qq   = bid >> 1;
    const int nt   = qq & 15;
    const int sp   = qq >> 4;
    const int h0   = (sp / 7) * 8, w0 = (sp % 7) * 8;
    const int co0  = co_t * 128;
    const int n0   = nt * 2;

    f32x16 acc[2][2];
    #pragma unroll
    for (int m = 0; m < 2; ++m)
        #pragma unroll
        for (int j = 0; j < 2; ++j)
            #pragma unroll
            for (int e = 0; e < 16; ++e) acc[m][j][e] = 0.f;

    auto STAGE_X = [&](int ck, int buf) {
        #pragma unroll
        for (int k = 0; k < 4; ++k) {
            const int s = t + k*256;           // 0..799
            if (s < 800) {
                const int cell = s >> 2, g = s & 3;
                const int im = cell / 100, r100 = cell % 100;
                const int r = r100 / 10, c = r100 % 10;
                const unsigned go = (((unsigned)(n0+im)*58u + (unsigned)(h0+r))*58u
                                     + (unsigned)(w0+c))*256u
                                    + (unsigned)ck*32u + (unsigned)g*8u;
                gld16(xs + go, &sXc[buf][(unsigned)s*8u]);
            }
        }
    };

    // wpf base for (cg = co_t*4 + wc*2 + m): per (ck,ks): 9 taps x 512 u16
    const u16* wb = wpf + (unsigned)lane*8u;
    #define APTR(ck, m, ks, tap) \
        reinterpret_cast<const f16x8*>(wb + \
            ((((unsigned)(ck)*8u + (unsigned)(co_t*4 + wc*2 + (m)))*2u + (unsigned)(ks))*9u \
              + (unsigned)(tap))*512u)

    STAGE_X(0, 0);
    __syncthreads();                           // sX chunk0 landed

    for (int ck = 0; ck < 8; ++ck) {
        const int buf = ck & 1;

        // ---- A(ks=0): 18 global b128, lane-linear ----
        f16x8 A[2][9];
        #pragma unroll
        for (int m = 0; m < 2; ++m)
            #pragma unroll
            for (int tap = 0; tap < 9; ++tap)
                A[m][tap] = *APTR(ck, m, 0, tap);

        if (ck < 7) STAGE_X(ck + 1, buf ^ 1);  // in flight across the chunk

        // ---- ks = 0 pass ----
        #pragma unroll
        for (int tap = 0; tap < 9; ++tap) {
            const int kh = tap / 3, kw = tap % 3;
            #pragma unroll
            for (int j = 0; j < 2; ++j) {
                const int cell = iwv*100 + (j*4 + (s5 >> 3) + kh)*10 + (s5 & 7) + kw;
                const f16x8 b = *reinterpret_cast<const f16x8*>(
                    &sXc[buf][(unsigned)cell*32u + (unsigned)khi*8u]);
                #pragma unroll
                for (int m = 0; m < 2; ++m)
                    acc[m][j] = __builtin_amdgcn_mfma_f32_32x32x16_f16(
                        A[m][tap], b, acc[m][j], 0, 0, 0);
            }
        }

        // ---- A(ks=1) ----
        f16x8 A1[2][9];
        #pragma unroll
        for (int m = 0; m < 2; ++m)
            #pragma unroll
            for (int tap = 0; tap < 9; ++tap)
                A1[m][tap] = *APTR(ck, m, 1, tap);

        // ---- ks = 1 pass ----
        #pragma unroll
        for (int tap = 0; tap < 9; ++tap) {
            const int kh = tap / 3, kw = tap % 3;
            #pragma unroll
            for (int j = 0; j < 2; ++j) {
                const int cell = iwv*100 + (j*4 + (s5 >> 3) + kh)*10 + (s5 & 7) + kw;
                const f16x8 b = *reinterpret_cast<const f16x8*>(
                    &sXc[buf][(unsigned)cell*32u + (unsigned)(2 + khi)*8u]);
                #pragma unroll
                for (int m = 0; m < 2; ++m)
                    acc[m][j] = __builtin_amdgcn_mfma_f32_32x32x16_f16(
                        A1[m][tap], b, acc[m][j], 0, 0, 0);
            }
        }

        __syncthreads();   // buf reads done; ck+1 staging landed (vmcnt drain)
    }
    #undef APTR

    // ---- epilogue (HW-verified R5/R6): col=lane&31 -> (pr,pc);
    //      row=(reg&3)+8*(reg>>2)+4*khi -> co ----
    const int n_img = n0 + iwv;
    #pragma unroll
    for (int m = 0; m < 2; ++m) {
        #pragma unroll
        for (int q = 0; q < 4; ++q) {
            const int cob = co0 + wc*64 + m*32 + 8*q + 4*khi;
            const float4 bv = *reinterpret_cast<const float4*>(&bias[cob]);
            const float bvv[4] = {bv.x, bv.y, bv.z, bv.w};
            #pragma unroll
            for (int j = 0; j < 2; ++j) {
                const int pr = j*4 + (s5 >> 3), pc = s5 & 7;
                #pragma unroll
                for (int rr = 0; rr < 4; ++rr) {
                    const int reg = q*4 + rr;
                    const unsigned yo =
                        (((unsigned)(n_img*COUT + cob + rr))*56u + (unsigned)(h0+pr))*56u
                        + (unsigned)(w0+pc);
                    y[yo] = acc[m][j][reg] + bvv[rr];
                }
            }
        }
    }
}

// ---- fp32 fallback if ws_size is insufficient ----
#define BM 128
#define KC 8
__global__ __launch_bounds__(256, 3) void conv3x3_f32(
    const float* __restrict__ x, const float* __restrict__ wgt,
    const float* __restrict__ bias, float* __restrict__ y) {
    __shared__ float sW[KC * 9][BM];
    __shared__ float sX[KC][10][12];
    const int t = threadIdx.x;
    const int tco = t >> 4, tsp = t & 15;
    const int srow = tsp >> 1, scol0 = (tsp & 1) * 4;
    const int bid = blockIdx.x;
    const int co_t = bid / (49 * NB);
    const int rem = bid % (49 * NB);
    const int sp_t = rem / NB, n = rem % NB;
    const int h0 = (sp_t / 7) * 8, w0 = (sp_t % 7) * 8;
    const int co0 = co_t * BM;
    float acc[8][4];
    #pragma unroll
    for (int r = 0; r < 8; ++r)
        #pragma unroll
        for (int j = 0; j < 4; ++j) acc[r][j] = 0.f;
    const int co_l = t >> 1, half = t & 1;
    for (int ci0 = 0; ci0 < CIN; ci0 += KC) {
        __syncthreads();
        {
            const float4* wsrc = reinterpret_cast<const float4*>(
                wgt + (size_t)(co0 + co_l) * (CIN * 9) + ci0 * 9 + half * 36);
            #pragma unroll
            for (int q = 0; q < 9; ++q) {
                float4 v = wsrc[q];
                const int k0 = half * 36 + q * 4;
                sW[k0 + 0][co_l] = v.x; sW[k0 + 1][co_l] = v.y;
                sW[k0 + 2][co_l] = v.z; sW[k0 + 3][co_l] = v.w;
            }
        }
        for (int idx = t; idx < KC * 100; idx += 256) {
            const int c = idx / 100, r = (idx % 100) / 10, cc = idx % 10;
            const int hh = h0 + r - 1, ww = w0 + cc - 1;
            float v = 0.f;
            if (hh >= 0 && hh < HH && ww >= 0 && ww < WW)
                v = x[(((size_t)n * CIN + (ci0 + c)) * HH + hh) * WW + ww];
            sX[c][r][cc] = v;
        }
        __syncthreads();
        for (int c = 0; c < KC; ++c) {
            #pragma unroll
            for (int kh = 0; kh < 3; ++kh) {
                float xw[8];
                *reinterpret_cast<float4*>(&xw[0]) =
                    *reinterpret_cast<const float4*>(&sX[c][srow + kh][scol0]);
                *reinterpret_cast<float4*>(&xw[4]) =
                    *reinterpret_cast<const float4*>(&sX[c][srow + kh][scol0 + 4]);
                #pragma unroll
                for (int kw = 0; kw < 3; ++kw) {
                    const int kidx = c * 9 + kh * 3 + kw;
                    float wv[8];
                    *reinterpret_cast<float4*>(&wv[0]) =
                        *reinterpret_cast<const float4*>(&sW[kidx][tco * 8]);
                    *reinterpret_cast<float4*>(&wv[4]) =
                        *reinterpret_cast<const float4*>(&sW[kidx][tco * 8 + 4]);
                    #pragma unroll
                    for (int r = 0; r < 8; ++r)
                        #pragma unroll
                        for (int j = 0; j < 4; ++j)
                            acc[r][j] = fmaf(wv[r], xw[kw + j], acc[r][j]);
                }
            }
        }
    }
    const int h = h0 + srow, wc2 = w0 + scol0;
    #pragma unroll
    for (int r = 0; r < 8; ++r) {
        const int co = co0 + tco * 8 + r;
        const float bv = bias[co];
        float4 o;
        o.x = acc[r][0] + bv; o.y = acc[r][1] + bv;
        o.z = acc[r][2] + bv; o.w = acc[r][3] + bv;
        *reinterpret_cast<float4*>(
            &y[(((size_t)n * COUT + co) * HH + h) * WW + wc2]) = o;
    }
}

extern "C" void kernel_launch(void* const* d_in, const int* in_sizes, int n_in,
                              void* d_out, int out_size, void* d_ws, size_t ws_size,
                              hipStream_t stream) {
    const float* x    = (const float*)d_in[0];
    const float* wgt  = (const float*)d_in[1];
    const float* bias = (const float*)d_in[2];
    float* y          = (float*)d_out;

    if (ws_size < WS_NEED) {
        conv3x3_f32<<<2 * 49 * NB, 256, 0, stream>>>(x, wgt, bias, y);
        return;
    }

    u16* xs  = (u16*)d_ws;
    u16* wpf = (u16*)((char*)d_ws + XS_BYTES);

    halo_zero<<<(int)((32u*228u*32u + 255u)/256u), 256, 0, stream>>>(xs);
    xcvt<<<32*8*56, 256, 0, stream>>>(x, xs);
    wcvt<<<(int)((WPF_ELEMS + 255u)/256u), 256, 0, stream>>>(wgt, wpf);
    conv_mfma<<<2*49*16, 256, 0, stream>>>(xs, wpf, bias, y);
}